// Round 12
// baseline (185.574 us; speedup 1.0000x reference)
//
#include <hip/hip_runtime.h>
#include <cstdint>
#include <cstddef>

// Problem constants
#define BB 2
#define SS 2048
#define DD 1024
#define HH 16
#define HDIM 64
// Attention scale 1/sqrt(64)=0.125 and the exp->exp2 fold log2(e) are
// pre-multiplied into q at the gemm_qkv epilogue: 0.125*1.4426950 = 0.18033688.

typedef short bf16x8 __attribute__((ext_vector_type(8)));
typedef short bf16x4 __attribute__((ext_vector_type(4)));
typedef float f32x4 __attribute__((ext_vector_type(4)));
typedef float f32x2 __attribute__((ext_vector_type(2)));

union U4S8 { uint4 u; bf16x8 s; };
union U2S4 { uint2 u; bf16x4 s; unsigned short h[4]; };

#if defined(__HIP_DEVICE_COMPILE__)
# if __has_builtin(__builtin_amdgcn_exp2f)
#  define EXP2(x) __builtin_amdgcn_exp2f(x)   // bare v_exp_f32, no libm envelope
# else
#  define EXP2(x) exp2f(x)
# endif
#else
# define EXP2(x) exp2f(x)
#endif

__device__ __forceinline__ unsigned short f2bf(float f) {
    union { float f; unsigned int u; } c; c.f = f;
    unsigned int u = c.u;
    unsigned int r = (u + 0x7FFFu + ((u >> 16) & 1u)) >> 16;  // RTNE
    return (unsigned short)r;
}

// async global->LDS, 16B per lane. LDS dest must be wave-uniform base + lane*16.
__device__ __forceinline__ void async_cp16(const void* g, void* l) {
    __builtin_amdgcn_global_load_lds(
        (const __attribute__((address_space(1))) void*)g,
        (__attribute__((address_space(3))) void*)l, 16, 0, 0);
}

// ---------------------------------------------------------------- fp32 -> bf16
// One kernel for all three inputs (x:524288, w_qkv:393216, w_out:131072 uint4s).
__global__ __launch_bounds__(256) void cvt_all(
    const float* __restrict__ x, const float* __restrict__ wq,
    const float* __restrict__ wo,
    unsigned short* __restrict__ xb, unsigned short* __restrict__ wqb,
    unsigned short* __restrict__ wob) {
    int i = blockIdx.x * 256 + threadIdx.x;
    const float* in; unsigned short* out; int j;
    if (i < 524288)       { in = x;  out = xb;  j = i; }
    else if (i < 917504)  { in = wq; out = wqb; j = i - 524288; }
    else                  { in = wo; out = wob; j = i - 917504; }
    float4 a = ((const float4*)in)[2 * j];
    float4 b = ((const float4*)in)[2 * j + 1];
    union { uint4 u; unsigned short h[8]; } o;
    o.h[0] = f2bf(a.x); o.h[1] = f2bf(a.y); o.h[2] = f2bf(a.z); o.h[3] = f2bf(a.w);
    o.h[4] = f2bf(b.x); o.h[5] = f2bf(b.y); o.h[6] = f2bf(b.z); o.h[7] = f2bf(b.w);
    ((uint4*)out)[j] = o.u;
}

// ---------------------------------------------------------------- QKV GEMM
// C[m,e] = sum_d x[m,d] * w_qkv[e,d]  (NT). M=4096, N=3072, K=1024.
// r19 (MEASURED WIN: gemm_qkv 55 -> ~31us inferred; total 202 -> 178.6):
// BK=32, 4-deep LDS ring (4 x 32KB = 128KB), stage tile t+3 during tile t,
// ONE vmcnt(8) + ONE barrier per K-tile -> each tile's 4 staging ops get
// 2-3 K-tiles of slack before their wait. Unchanged this round.
__global__ __launch_bounds__(512, 2) void gemm_qkv(
    const unsigned short* __restrict__ A,   // x_bf   [4096][1024]
    const unsigned short* __restrict__ Bw,  // wqkv_bf[3072][1024]
    unsigned short* __restrict__ qb, unsigned short* __restrict__ kb,
    unsigned short* __restrict__ vb) {
    const int K = 1024;
    __shared__ unsigned short smem[65536];  // 128 KB: 4 bufs x [A 8192 | B 8192]
    int tid = threadIdx.x;
    int lane = tid & 63, wave = tid >> 6;
    int wmp = wave & 1, wnp = wave >> 1;
    int lm = lane & 15, lq = lane >> 4;

    // XCD-chunked bijective swizzle: 192 blocks = 8 XCDs x 24
    int id = blockIdx.y * 12 + blockIdx.x;
    int swz = (id & 7) * 24 + (id >> 3);
    int m0 = (swz / 12) * 256, n0 = (swz % 12) * 256;

    f32x4 acc[8][4] = {};

    // ---- staging addressing (pre-swizzled global source, linear LDS dest)
    int u2 = tid >> 2;                        // row-within-op 0..127
    int c2 = (tid & 3) ^ (u2 & 3);            // swizzled source chunk
    int sdst = tid * 8;                       // LDS dest (shorts)
    const unsigned short* gA0 = A  + (size_t)(m0 + u2) * K + c2 * 8;
    const unsigned short* gB0 = Bw + (size_t)(n0 + u2) * K + c2 * 8;
    const unsigned short* gA1 = gA0 + (size_t)128 * K;
    const unsigned short* gB1 = gB0 + (size_t)128 * K;

    // stage all 4 ops of one K-tile into buf j at column kk (shorts)
#define STAGE4(j, kk) do {                                                  \
        async_cp16(gA0 + (kk), smem + (j) * 16384 + 0     + sdst);          \
        async_cp16(gA1 + (kk), smem + (j) * 16384 + 4096  + sdst);          \
        async_cp16(gB0 + (kk), smem + (j) * 16384 + 8192  + sdst);          \
        async_cp16(gB1 + (kk), smem + (j) * 16384 + 12288 + sdst);          \
    } while (0)

    // ---- fragment read addressing (swizzled chunk, balanced banks)
    // A row r = wmp*128 + m*16 + lm; offset = r*32 + ((lq^(lm&3)))*8
    int axk = (lq ^ (lm & 3)) * 8;
    int aBase = (wmp * 128 + lm) * 32 + axk;
    int bBase = 8192 + (wnp * 64 + lm) * 32 + axk;
    U4S8 af[8], bfr[4];

    // One K-tile: 12 ds_read_b128 + 4 staging ops (tile t+3) + 32 MFMA +
    // vmcnt(8) (retires tile t+1's 4 ops; t+2/t+3 stay in flight) + barrier.
#define KT(j, kk3) do {                                                     \
        _Pragma("unroll")                                                   \
        for (int m = 0; m < 8; m++)                                         \
            af[m].u = *(const uint4*)(smem + (j) * 16384 + aBase + m * 512);\
        _Pragma("unroll")                                                   \
        for (int n = 0; n < 4; n++)                                         \
            bfr[n].u = *(const uint4*)(smem + (j) * 16384 + bBase + n * 512);\
        STAGE4((((j) + 3) & 3), kk3);                                       \
        _Pragma("unroll")                                                   \
        for (int m = 0; m < 8; m++)                                         \
            _Pragma("unroll")                                               \
            for (int n = 0; n < 4; n++)                                     \
                acc[m][n] = __builtin_amdgcn_mfma_f32_16x16x32_bf16(        \
                    af[m].s, bfr[n].s, acc[m][n], 0, 0, 0);                 \
        asm volatile("s_waitcnt vmcnt(8)" ::: "memory");                    \
        __builtin_amdgcn_s_barrier();                                       \
    } while (0)

    // prologue: stage tiles 0,1,2 (12 ops, tile-FIFO order); vmcnt(8)
    // retires tile 0's 4 ops before the first read.
    STAGE4(0, 0); STAGE4(1, 32); STAGE4(2, 64);
    asm volatile("s_waitcnt vmcnt(8)" ::: "memory");
    __builtin_amdgcn_s_barrier();

    // 32 K-tiles of BK=32; prefetch kk = (t+3)*32. Tail prefetches (t>=29)
    // over-read into adjacent ws buffers (never consumed, in-bounds of ws).
    #pragma unroll 1
    for (int t4 = 0; t4 < 8; ++t4) {
        int kb128 = t4 * 128;
        KT(0, kb128 + 96);
        KT(1, kb128 + 128);
        KT(2, kb128 + 160);
        KT(3, kb128 + 192);
    }
#undef KT
#undef STAGE4

    asm volatile("s_waitcnt vmcnt(0)" ::: "memory");  // drain stray over-read loads
    __builtin_amdgcn_s_barrier();                     // staging LDS done before reuse

    // Epilogue. C/D layout: col=lane&15, row=(lane>>4)*4+reg.
    // acc[mi][ni] -> C row m0+wm+mi*16+lq*4+r, col n0+wn+ni*16+lm.
    // Two 64-row chunks (mi-half) through an 8 KiB/wave LDS transpose buffer.
    unsigned short* Lw = smem + wave * 8192;  // uses 64 x 72
    int wm = wmp * 128, wn = wnp * 64;
    int b = m0 >> 11;
    int s_base = (m0 + wm) & 2047;
    int h = ((n0 + wn) >> 6) & 15;
    if (n0 < 1024) {
        // ---- v: transpose (store [B,H,HD,S]): Lw[hd][s], b64 packed writes
        unsigned short* vdst = vb + ((size_t)(b * HH + h) * HDIM) * SS;
        #pragma unroll
        for (int c = 0; c < 2; c++) {
            #pragma unroll
            for (int m4 = 0; m4 < 4; m4++)
                #pragma unroll
                for (int ni = 0; ni < 4; ni++) {
                    U2S4 t;
                    #pragma unroll
                    for (int r = 0; r < 4; r++)
                        t.h[r] = f2bf(acc[c * 4 + m4][ni][r]);
                    *(uint2*)&Lw[(ni * 16 + lm) * 72 + m4 * 16 + lq * 4] = t.u;
                }
            __builtin_amdgcn_wave_barrier();
            #pragma unroll
            for (int it = 0; it < 8; it++) {
                int hd = it * 8 + (lane >> 3);
                int so = (lane & 7) * 8;
                uint4 val = *(const uint4*)&Lw[hd * 72 + so];
                *(uint4*)(vdst + (size_t)hd * SS + s_base + c * 64 + so) = val;
            }
            __builtin_amdgcn_wave_barrier();
        }
    } else {
        // ---- q/k: gather (store [B,H,S,HD]): Lw[s][hd], no transpose
        bool isq = n0 < 2048;
        unsigned short* dst = isq ? qb : kb;
        float scale = isq ? 0.18033688f : 1.0f;  // q: fold softmax scale * log2(e)
        unsigned short* qdst = dst + ((size_t)(b * HH + h) * SS) * HDIM;
        #pragma unroll
        for (int c = 0; c < 2; c++) {
            #pragma unroll
            for (int m4 = 0; m4 < 4; m4++)
                #pragma unroll
                for (int ni = 0; ni < 4; ni++)
                    #pragma unroll
                    for (int r = 0; r < 4; r++)
                        Lw[(m4 * 16 + lq * 4 + r) * 72 + ni * 16 + lm] =
                            f2bf(acc[c * 4 + m4][ni][r] * scale);
            __builtin_amdgcn_wave_barrier();
            #pragma unroll
            for (int it = 0; it < 8; it++) {
                int srw = it * 8 + (lane >> 3);
                int so = (lane & 7) * 8;
                uint4 val = *(const uint4*)&Lw[srw * 72 + so];
                *(uint4*)(qdst + (size_t)(s_base + c * 64 + srw) * HDIM + so) = val;
            }
            __builtin_amdgcn_wave_barrier();
        }
    }
}

// ---------------------------------------------------------------- Flash attention
// r20: r19's depth lesson applied to attn. r15-r19 structure drained
// vmcnt(0) per 128-pair via __syncthreads -> each staged pair had ~1
// compute phase of slack (the r18 disease; attn PMC: MfmaUtil 26.8,
// VALU 38.7, occ 32.7, HBM 21% -- ~50% stall). Now: 4-deep pair ring
// (4 x 32KB = 128KB LDS), stage pair t+3 during pair t, ONE vmcnt(8) +
// raw s_barrier per pair (~3 phases slack). Occupancy 2->1 block/CU --
// gemm r19 measured depth > TLP on this chip. Plus T12: P->bf16 via
// v_cvt_pk_bf16_f32 (2 ops) instead of 4 bit-adds + 2 perms (RTNE vs
// ties-away: <=1ulp bf16). Tail stages (t>=13) over-read into adjacent
// ws buffers; drained by vmcnt(0) before the epilogue reuses LDS.
__global__ __launch_bounds__(512) void attn(
    const unsigned short* __restrict__ qb,  // [B,H,S,HD] pre-scaled (incl. log2e)
    const unsigned short* __restrict__ kb,  // [B,H,S,HD]
    const unsigned short* __restrict__ vb,  // [B,H,HD,S] (transposed)
    unsigned short* __restrict__ ob) {      // [B,S,D]
    int bh = blockIdx.y;
    int q0 = blockIdx.x * 128;
    int tid = threadIdx.x, lane = tid & 63, wave = tid >> 6;
    int grp = wave >> 2;      // k-half
    int w4  = wave & 3;       // wave-in-group: owns q rows w4*32..+31
    int lm = lane & 15, lq = lane >> 4;

    // 4 pair-bufs x [KA|KB|VA|VB, 4096 shorts each] = 65536 shorts = 128 KB
    __shared__ unsigned short smem[65536];
    float* smf = (float*)smem;

    const unsigned short* qg = qb + (size_t)bh * SS * HDIM;
    const unsigned short* kg = kb + (size_t)bh * SS * HDIM;
    const unsigned short* vg = vb + (size_t)bh * HDIM * SS;

    // Q fragments (both groups load the same q rows for their k-half)
    U4S8 qf[2][2];
    #pragma unroll
    for (int qt = 0; qt < 2; qt++)
        #pragma unroll
        for (int ks = 0; ks < 2; ks++)
            qf[qt][ks].u = *(const uint4*)(
                qg + (size_t)(q0 + w4 * 32 + qt * 16 + lm) * HDIM + ks * 32 + lq * 8);

    f32x4 oacc[4][2] = {};        // O^T[hd-tile][q-subtile] (this group's k-half)
    f32x2 lsum2[2] = {};

    // ---- loop-invariant swizzled LDS read indices within a 64x64 tile (shorts)
    int lm7 = lm & 7;
    int kidx = lm * 64 + 8 * (lq ^ lm7);          // kf b128 (slot rows)
    int vidx[2];                                  // vf b128: kpos kb*32+lq*8 (true k)
    #pragma unroll
    for (int kblk = 0; kblk < 2; kblk++)
        vidx[kblk] = lm * 64 + 8 * (((kblk << 2) | lq) ^ lm7);

    // ---- staging: 512 threads x 4 async-16B = one 128-wide K-tile (K + V)
    // K source row is KAPPA-permuted: LDS slot s holds k-row kappa(s), where
    // kappa(s) = 32*(s>>5) + 8*((s>>2)&3) + 4*((s>>4)&1) + (s&3)  (s in 0..63)
    int sr  = tid >> 3;                // LDS slot row 0..63
    int s5  = sr & 31;
    int kap = (sr & 32) + (((s5 >> 2) & 3) << 3) + (((s5 >> 4) & 1) << 2) + (s5 & 3);
    int lch = (tid & 7) ^ (sr & 7);    // chunk swizzle keyed by SLOT row
    int sdst = tid * 8;                // shorts within each 4096-short region
    const unsigned short* kpA = kg + (size_t)kap * HDIM + lch * 8;   // slots 0-63
    const unsigned short* kpB = kpA + 64 * HDIM;                     // slots 64-127
    const unsigned short* vpA = vg + (size_t)sr * SS + lch * 8;      // kpos 0-63
    const unsigned short* vpB = vpA + 64;                            // kpos 64-127

    #define STAGE(pbase)                                                       \
        do {                                                                   \
            async_cp16(kpA, smem + (pbase) + sdst);                            \
            async_cp16(kpB, smem + (pbase) + 4096 + sdst);                     \
            async_cp16(vpA, smem + (pbase) + 8192 + sdst);                     \
            async_cp16(vpB, smem + (pbase) + 12288 + sdst);                    \
            kpA += 128 * HDIM; kpB += 128 * HDIM; vpA += 128; vpB += 128;      \
        } while (0)

    // prologue: stage pairs 0,1,2 (12 ops); vmcnt(8) retires pair 0.
    STAGE(0); STAGE(16384); STAGE(32768);
    asm volatile("s_waitcnt vmcnt(8)" ::: "memory");
    __builtin_amdgcn_s_barrier();

    #pragma unroll 1
    for (int t = 0; t < 16; ++t) {
        int cb = (t & 3) << 14;              // compute buf (pair t)
        STAGE(((t + 3) & 3) << 14);          // issue pair t+3 (t>=13: over-read)

        int kbase = cb + grp * 4096;
        int vbase = cb + 8192 + grp * 4096;

        // ---- S^T then P^T = 2^(S^T): tile-pair halves fill the K=32
        //      B-operand directly (kappa staging makes r-index == j)
        U4S8 pb8[2][2];   // [kblk][qt]: full 16x16x32 B-operand fragments
        #pragma unroll
        for (int mi = 0; mi < 4; mi++) {
            U4S8 kf0, kf1;
            kf0.u = *(const uint4*)(smem + kbase + mi * 1024 + kidx);
            kf1.u = *(const uint4*)(smem + kbase + mi * 1024 + (kidx ^ 32));
            #pragma unroll
            for (int qt = 0; qt < 2; qt++) {
                f32x4 sa = {};
                sa = __builtin_amdgcn_mfma_f32_16x16x32_bf16(kf0.s, qf[qt][0].s, sa, 0, 0, 0);
                sa = __builtin_amdgcn_mfma_f32_16x16x32_bf16(kf1.s, qf[qt][1].s, sa, 0, 0, 0);
                float p0 = EXP2(sa[0]);
                float p1 = EXP2(sa[1]);
                float p2 = EXP2(sa[2]);
                float p3 = EXP2(sa[3]);
                f32x2 a01; a01[0] = p0; a01[1] = p1;
                f32x2 a23; a23[0] = p2; a23[1] = p3;
                lsum2[qt] += a01;
                lsum2[qt] += a23;
                unsigned int lo, hi;   // T12: pack 2 f32 -> 2 bf16, one op each
                asm("v_cvt_pk_bf16_f32 %0, %1, %2" : "=v"(lo) : "v"(p0), "v"(p1));
                asm("v_cvt_pk_bf16_f32 %0, %1, %2" : "=v"(hi) : "v"(p2), "v"(p3));
                if ((mi & 1) == 0) { pb8[mi >> 1][qt].u.x = lo; pb8[mi >> 1][qt].u.y = hi; }
                else               { pb8[mi >> 1][qt].u.z = lo; pb8[mi >> 1][qt].u.w = hi; }
            }
        }

        // ---- O^T += V^T·P^T at K=32
        #pragma unroll
        for (int mi2 = 0; mi2 < 4; mi2++) {
            #pragma unroll
            for (int kblk = 0; kblk < 2; kblk++) {
                U4S8 vf;
                vf.u = *(const uint4*)(smem + vbase + mi2 * 1024 + vidx[kblk]);
                oacc[mi2][0] = __builtin_amdgcn_mfma_f32_16x16x32_bf16(
                    vf.s, pb8[kblk][0].s, oacc[mi2][0], 0, 0, 0);
                oacc[mi2][1] = __builtin_amdgcn_mfma_f32_16x16x32_bf16(
                    vf.s, pb8[kblk][1].s, oacc[mi2][1], 0, 0, 0);
            }
        }

        // retire pair t+1's ops (t+2, t+3 stay in flight)
        asm volatile("s_waitcnt vmcnt(8)" ::: "memory");
        __builtin_amdgcn_s_barrier();
    }
    #undef STAGE

    // ---- per-group row sums (lanes lm,+16,+32,+48 hold disjoint k partials)
    float gsum[2];
    #pragma unroll
    for (int qt = 0; qt < 2; qt++) {
        float s = lsum2[qt][0] + lsum2[qt][1];
        s += __shfl_xor(s, 16);
        s += __shfl_xor(s, 32);
        gsum[qt] = s;
    }

    asm volatile("s_waitcnt vmcnt(0)" ::: "memory");  // stray tail stages land
    __syncthreads();  // all compute + LDS writes done before epilogue reuse

    // ---- group 1 publishes raw O^T + sums (SoA: word j at j*64+lane, no conflicts)
    if (grp == 1) {
        float* pub = smf + w4 * 2048;
        #pragma unroll
        for (int mi2 = 0; mi2 < 4; mi2++)
            #pragma unroll
            for (int qt = 0; qt < 2; qt++)
                #pragma unroll
                for (int r = 0; r < 4; r++)
                    pub[(mi2 * 8 + qt * 4 + r) * 64 + lane] = oacc[mi2][qt][r];
        if (lq == 0) {
            smf[8192 + w4 * 32 + lm]      = gsum[0];
            smf[8192 + w4 * 32 + 16 + lm] = gsum[1];
        }
    }
    __syncthreads();

    // ---- group 0 combines, normalizes, writes output
    if (grp == 0) {
        float* pub = smf + w4 * 2048;
        #pragma unroll
        for (int mi2 = 0; mi2 < 4; mi2++)
            #pragma unroll
            for (int qt = 0; qt < 2; qt++)
                #pragma unroll
                for (int r = 0; r < 4; r++)
                    oacc[mi2][qt][r] += pub[(mi2 * 8 + qt * 4 + r) * 64 + lane];
        float inv[2];
        inv[0] = 1.f / (gsum[0] + smf[8192 + w4 * 32 + lm]);
        inv[1] = 1.f / (gsum[1] + smf[8192 + w4 * 32 + 16 + lm]);

        // transpose O^T back via smem (region disjoint from publish), coalesced store
        unsigned short* Ow = smem + 17024 + w4 * 2304;  // 32 x 72
        #pragma unroll
        for (int mi2 = 0; mi2 < 4; mi2++)
            #pragma unroll
            for (int qt = 0; qt < 2; qt++) {
                U2S4 t;
                #pragma unroll
                for (int r = 0; r < 4; r++)
                    t.h[r] = f2bf(oacc[mi2][qt][r] * inv[qt]);
                *(uint2*)&Ow[(qt * 16 + lm) * 72 + mi2 * 16 + lq * 4] = t.u;
            }
        __builtin_amdgcn_wave_barrier();  // Ow wave-local
        int b = bh >> 4, h = bh & 15;
        #pragma unroll
        for (int it = 0; it < 4; it++) {
            int q  = it * 8 + (lane >> 3);
            int off = (lane & 7) * 8;
            uint4 val = *(const uint4*)&Ow[q * 72 + off];
            int srw = q0 + w4 * 32 + q;
            *(uint4*)(ob + (size_t)(b * SS + srw) * DD + h * 64 + off) = val;
        }
    }
}

// ---------------------------------------------------------------- Output GEMM
// out[m,e] = sum_d o[m,d] * w_out[e,d] + b_out[e].  M=4096, N=1024, K=1024.
// 128x64 tile -> 512 blocks (2/CU). r16: BK=64 per barrier (16 barriers,
// 16 MFMA/wave/barrier — was 32 barriers x 8) + XOR-swizzled LDS.
// Buffer layout (shorts): As_k0[0,4096) As_k1[4096,8192) Bs_k0[8192,10240)
// Bs_k1[10240,12288); dbuf at +12288. Total 24576 shorts = 48 KB.
__global__ __launch_bounds__(256) void gemm_out(
    const unsigned short* __restrict__ A,   // o_bf   [4096][1024]
    const unsigned short* __restrict__ Bw,  // wout_bf[1024][1024]
    const float* __restrict__ bias, float* __restrict__ out) {
    const int K = 1024;
    __shared__ unsigned short smem[24576];
    int tid = threadIdx.x;
    int lane = tid & 63, wave = tid >> 6;
    int wm = (wave & 1) * 64, wn = (wave >> 1) * 32;
    int m0 = blockIdx.y * 128, n0 = blockIdx.x * 64;
    int lm = lane & 15, lq = lane >> 4;

    f32x4 acc[4][2] = {};

    int sdst = tid * 8;
    int lch = (tid & 3) ^ ((tid >> 3) & 3);  // swizzled source chunk
    const unsigned short* gA = A  + (size_t)(m0 + (tid >> 2)) * K + lch * 8;
    const unsigned short* gB = Bw + (size_t)(n0 + (tid >> 2)) * K + lch * 8;
    int sw = (lq ^ ((lm >> 1) & 3)) * 8;     // swizzled read chunk offset

#define OSTAGE(k0, buf) do {                                               \
        async_cp16(gA + (k0),               smem + (buf) + sdst);          \
        async_cp16(gA + 64 * K + (k0),      smem + (buf) + 2048 + sdst);   \
        async_cp16(gA + (k0) + 32,          smem + (buf) + 4096 + sdst);   \
        async_cp16(gA + 64 * K + (k0) + 32, smem + (buf) + 6144 + sdst);   \
        async_cp16(gB + (k0),               smem + (buf) + 8192 + sdst);   \
        async_cp16(gB + (k0) + 32,          smem + (buf) + 10240 + sdst);  \
    } while (0)

    OSTAGE(0, 0);
    for (int k0 = 0; k0 < K; k0 += 128) {
        #pragma unroll
        for (int hf = 0; hf < 2; hf++) {
            int base = hf ? 12288 : 0;
            int obuf = hf ? 0 : 12288;
            __syncthreads();
            int kn = k0 + 64 + hf * 64;
            if (kn < K) OSTAGE(kn, obuf);
            #pragma unroll
            for (int kc = 0; kc < 2; kc++) {
                const unsigned short* As = smem + base + kc * 4096;
                const unsigned short* Bs = smem + base + 8192 + kc * 2048;
                U4S8 af[4], bfx[2];
                #pragma unroll
                for (int i = 0; i < 4; i++)
                    af[i].u = *(const uint4*)(As + (wm + i * 16 + lm) * 32 + sw);
                #pragma unroll
                for (int i = 0; i < 2; i++)
                    bfx[i].u = *(const uint4*)(Bs + (wn + i * 16 + lm) * 32 + sw);
                #pragma unroll
                for (int mi = 0; mi < 4; mi++)
                    #pragma unroll
                    for (int ni = 0; ni < 2; ni++)
                        acc[mi][ni] = __builtin_amdgcn_mfma_f32_16x16x32_bf16(
                            af[mi].s, bfx[ni].s, acc[mi][ni], 0, 0, 0);
            }
        }
    }
#undef OSTAGE

    #pragma unroll
    for (int mi = 0; mi < 4; mi++) {
        int gr = m0 + wm + mi * 16 + lq * 4;
        #pragma unroll
        for (int ni = 0; ni < 2; ni++) {
            int gc = n0 + wn + ni * 16 + lm;
            float bv = bias[gc];
            #pragma unroll
            for (int r = 0; r < 4; r++)
                out[(size_t)(gr + r) * DD + gc] = acc[mi][ni][r] + bv;
        }
    }
}

// ---------------------------------------------------------------- launch
extern "C" void kernel_launch(void* const* d_in, const int* in_sizes, int n_in,
                              void* d_out, int out_size, void* d_ws, size_t ws_size,
                              hipStream_t stream) {
    const float* x     = (const float*)d_in[0];
    const float* w_qkv = (const float*)d_in[1];
    const float* w_out = (const float*)d_in[2];
    const float* b_out = (const float*)d_in[3];
    float* out = (float*)d_out;

    unsigned short* ws = (unsigned short*)d_ws;
    const size_t NX = (size_t)BB * SS * DD;        // 4,194,304
    unsigned short* x_bf    = ws;
    unsigned short* wqkv_bf = x_bf + NX;
    unsigned short* wout_bf = wqkv_bf + 3145728;
    unsigned short* q_buf   = wout_bf + 1048576;
    unsigned short* k_buf   = q_buf + NX;
    unsigned short* v_buf   = k_buf + NX;
    unsigned short* o_buf   = v_buf + NX;

    cvt_all<<<4096, 256, 0, stream>>>(x, w_qkv, w_out, x_bf, wqkv_bf, wout_bf);
    gemm_qkv<<<dim3(12, 16), 512, 0, stream>>>(x_bf, wqkv_bf, q_buf, k_buf, v_buf);
    attn<<<dim3(16, 32), 512, 0, stream>>>(q_buf, k_buf, v_buf, o_buf);
    gemm_out<<<dim3(16, 32), 256, 0, stream>>>(o_buf, wout_bf, b_out, out);
}

// Round 13
// 172.062 us; speedup vs baseline: 1.0785x; 1.0785x over previous
//
#include <hip/hip_runtime.h>
#include <cstdint>
#include <cstddef>

// Problem constants
#define BB 2
#define SS 2048
#define DD 1024
#define HH 16
#define HDIM 64
// Attention scale 1/sqrt(64)=0.125 and the exp->exp2 fold log2(e) are
// pre-multiplied into q at the gemm_qkv epilogue: 0.125*1.4426950 = 0.18033688.

typedef short bf16x8 __attribute__((ext_vector_type(8)));
typedef short bf16x4 __attribute__((ext_vector_type(4)));
typedef float f32x4 __attribute__((ext_vector_type(4)));
typedef float f32x2 __attribute__((ext_vector_type(2)));

union U4S8 { uint4 u; bf16x8 s; };
union U2S4 { uint2 u; bf16x4 s; unsigned short h[4]; };

#if defined(__HIP_DEVICE_COMPILE__)
# if __has_builtin(__builtin_amdgcn_exp2f)
#  define EXP2(x) __builtin_amdgcn_exp2f(x)   // bare v_exp_f32, no libm envelope
# else
#  define EXP2(x) exp2f(x)
# endif
#else
# define EXP2(x) exp2f(x)
#endif

__device__ __forceinline__ unsigned short f2bf(float f) {
    union { float f; unsigned int u; } c; c.f = f;
    unsigned int u = c.u;
    unsigned int r = (u + 0x7FFFu + ((u >> 16) & 1u)) >> 16;  // RTNE
    return (unsigned short)r;
}

// async global->LDS, 16B per lane. LDS dest must be wave-uniform base + lane*16.
__device__ __forceinline__ void async_cp16(const void* g, void* l) {
    __builtin_amdgcn_global_load_lds(
        (const __attribute__((address_space(1))) void*)g,
        (__attribute__((address_space(3))) void*)l, 16, 0, 0);
}

// ---------------------------------------------------------------- fp32 -> bf16
// One kernel for all three inputs (x:524288, w_qkv:393216, w_out:131072 uint4s).
__global__ __launch_bounds__(256) void cvt_all(
    const float* __restrict__ x, const float* __restrict__ wq,
    const float* __restrict__ wo,
    unsigned short* __restrict__ xb, unsigned short* __restrict__ wqb,
    unsigned short* __restrict__ wob) {
    int i = blockIdx.x * 256 + threadIdx.x;
    const float* in; unsigned short* out; int j;
    if (i < 524288)       { in = x;  out = xb;  j = i; }
    else if (i < 917504)  { in = wq; out = wqb; j = i - 524288; }
    else                  { in = wo; out = wob; j = i - 917504; }
    float4 a = ((const float4*)in)[2 * j];
    float4 b = ((const float4*)in)[2 * j + 1];
    union { uint4 u; unsigned short h[8]; } o;
    o.h[0] = f2bf(a.x); o.h[1] = f2bf(a.y); o.h[2] = f2bf(a.z); o.h[3] = f2bf(a.w);
    o.h[4] = f2bf(b.x); o.h[5] = f2bf(b.y); o.h[6] = f2bf(b.z); o.h[7] = f2bf(b.w);
    ((uint4*)out)[j] = o.u;
}

// ---------------------------------------------------------------- QKV GEMM
// C[m,e] = sum_d x[m,d] * w_qkv[e,d]  (NT). M=4096, N=3072, K=1024.
// r19 (MEASURED WIN): BK=32, 4-deep LDS ring (4 x 32KB = 128KB), stage tile
// t+3 during tile t, ONE vmcnt(8) + ONE barrier per K-tile. Unchanged.
__global__ __launch_bounds__(512, 2) void gemm_qkv(
    const unsigned short* __restrict__ A,   // x_bf   [4096][1024]
    const unsigned short* __restrict__ Bw,  // wqkv_bf[3072][1024]
    unsigned short* __restrict__ qb, unsigned short* __restrict__ kb,
    unsigned short* __restrict__ vb) {
    const int K = 1024;
    __shared__ unsigned short smem[65536];  // 128 KB: 4 bufs x [A 8192 | B 8192]
    int tid = threadIdx.x;
    int lane = tid & 63, wave = tid >> 6;
    int wmp = wave & 1, wnp = wave >> 1;
    int lm = lane & 15, lq = lane >> 4;

    // XCD-chunked bijective swizzle: 192 blocks = 8 XCDs x 24
    int id = blockIdx.y * 12 + blockIdx.x;
    int swz = (id & 7) * 24 + (id >> 3);
    int m0 = (swz / 12) * 256, n0 = (swz % 12) * 256;

    f32x4 acc[8][4] = {};

    // ---- staging addressing (pre-swizzled global source, linear LDS dest)
    int u2 = tid >> 2;                        // row-within-op 0..127
    int c2 = (tid & 3) ^ (u2 & 3);            // swizzled source chunk
    int sdst = tid * 8;                       // LDS dest (shorts)
    const unsigned short* gA0 = A  + (size_t)(m0 + u2) * K + c2 * 8;
    const unsigned short* gB0 = Bw + (size_t)(n0 + u2) * K + c2 * 8;
    const unsigned short* gA1 = gA0 + (size_t)128 * K;
    const unsigned short* gB1 = gB0 + (size_t)128 * K;

    // stage all 4 ops of one K-tile into buf j at column kk (shorts)
#define STAGE4(j, kk) do {                                                  \
        async_cp16(gA0 + (kk), smem + (j) * 16384 + 0     + sdst);          \
        async_cp16(gA1 + (kk), smem + (j) * 16384 + 4096  + sdst);          \
        async_cp16(gB0 + (kk), smem + (j) * 16384 + 8192  + sdst);          \
        async_cp16(gB1 + (kk), smem + (j) * 16384 + 12288 + sdst);          \
    } while (0)

    // ---- fragment read addressing (swizzled chunk, balanced banks)
    int axk = (lq ^ (lm & 3)) * 8;
    int aBase = (wmp * 128 + lm) * 32 + axk;
    int bBase = 8192 + (wnp * 64 + lm) * 32 + axk;
    U4S8 af[8], bfr[4];

    // One K-tile: 12 ds_read_b128 + 4 staging ops (tile t+3) + 32 MFMA +
    // vmcnt(8) (retires tile t+1's 4 ops; t+2/t+3 stay in flight) + barrier.
#define KT(j, kk3) do {                                                     \
        _Pragma("unroll")                                                   \
        for (int m = 0; m < 8; m++)                                         \
            af[m].u = *(const uint4*)(smem + (j) * 16384 + aBase + m * 512);\
        _Pragma("unroll")                                                   \
        for (int n = 0; n < 4; n++)                                         \
            bfr[n].u = *(const uint4*)(smem + (j) * 16384 + bBase + n * 512);\
        STAGE4((((j) + 3) & 3), kk3);                                       \
        _Pragma("unroll")                                                   \
        for (int m = 0; m < 8; m++)                                         \
            _Pragma("unroll")                                               \
            for (int n = 0; n < 4; n++)                                     \
                acc[m][n] = __builtin_amdgcn_mfma_f32_16x16x32_bf16(        \
                    af[m].s, bfr[n].s, acc[m][n], 0, 0, 0);                 \
        asm volatile("s_waitcnt vmcnt(8)" ::: "memory");                    \
        __builtin_amdgcn_s_barrier();                                       \
    } while (0)

    // prologue: stage tiles 0,1,2 (12 ops, tile-FIFO order); vmcnt(8)
    // retires tile 0's 4 ops before the first read.
    STAGE4(0, 0); STAGE4(1, 32); STAGE4(2, 64);
    asm volatile("s_waitcnt vmcnt(8)" ::: "memory");
    __builtin_amdgcn_s_barrier();

    // 32 K-tiles of BK=32; prefetch kk = (t+3)*32. Tail prefetches (t>=29)
    // over-read into adjacent ws buffers (never consumed, in-bounds of ws).
    #pragma unroll 1
    for (int t4 = 0; t4 < 8; ++t4) {
        int kb128 = t4 * 128;
        KT(0, kb128 + 96);
        KT(1, kb128 + 128);
        KT(2, kb128 + 160);
        KT(3, kb128 + 192);
    }
#undef KT
#undef STAGE4

    asm volatile("s_waitcnt vmcnt(0)" ::: "memory");  // drain stray over-read loads
    __builtin_amdgcn_s_barrier();                     // staging LDS done before reuse

    // Epilogue. C/D layout: col=lane&15, row=(lane>>4)*4+reg.
    unsigned short* Lw = smem + wave * 8192;  // uses 64 x 72
    int wm = wmp * 128, wn = wnp * 64;
    int b = m0 >> 11;
    int s_base = (m0 + wm) & 2047;
    int h = ((n0 + wn) >> 6) & 15;
    if (n0 < 1024) {
        // ---- v: transpose (store [B,H,HD,S]): Lw[hd][s], b64 packed writes
        unsigned short* vdst = vb + ((size_t)(b * HH + h) * HDIM) * SS;
        #pragma unroll
        for (int c = 0; c < 2; c++) {
            #pragma unroll
            for (int m4 = 0; m4 < 4; m4++)
                #pragma unroll
                for (int ni = 0; ni < 4; ni++) {
                    U2S4 t;
                    #pragma unroll
                    for (int r = 0; r < 4; r++)
                        t.h[r] = f2bf(acc[c * 4 + m4][ni][r]);
                    *(uint2*)&Lw[(ni * 16 + lm) * 72 + m4 * 16 + lq * 4] = t.u;
                }
            __builtin_amdgcn_wave_barrier();
            #pragma unroll
            for (int it = 0; it < 8; it++) {
                int hd = it * 8 + (lane >> 3);
                int so = (lane & 7) * 8;
                uint4 val = *(const uint4*)&Lw[hd * 72 + so];
                *(uint4*)(vdst + (size_t)hd * SS + s_base + c * 64 + so) = val;
            }
            __builtin_amdgcn_wave_barrier();
        }
    } else {
        // ---- q/k: gather (store [B,H,S,HD]): Lw[s][hd], no transpose
        bool isq = n0 < 2048;
        unsigned short* dst = isq ? qb : kb;
        float scale = isq ? 0.18033688f : 1.0f;  // q: fold softmax scale * log2(e)
        unsigned short* qdst = dst + ((size_t)(b * HH + h) * SS) * HDIM;
        #pragma unroll
        for (int c = 0; c < 2; c++) {
            #pragma unroll
            for (int m4 = 0; m4 < 4; m4++)
                #pragma unroll
                for (int ni = 0; ni < 4; ni++)
                    #pragma unroll
                    for (int r = 0; r < 4; r++)
                        Lw[(m4 * 16 + lq * 4 + r) * 72 + ni * 16 + lm] =
                            f2bf(acc[c * 4 + m4][ni][r] * scale);
            __builtin_amdgcn_wave_barrier();
            #pragma unroll
            for (int it = 0; it < 8; it++) {
                int srw = it * 8 + (lane >> 3);
                int so = (lane & 7) * 8;
                uint4 val = *(const uint4*)&Lw[srw * 72 + so];
                *(uint4*)(qdst + (size_t)(s_base + c * 64 + srw) * HDIM + so) = val;
            }
            __builtin_amdgcn_wave_barrier();
        }
    }
}

// ---------------------------------------------------------------- Flash attention
// r21: REVERT to the measured-best r19 structure (64KB LDS, 2 blk/CU, stage
// next pair + __syncthreads per pair) -- r20's 4-deep ring cost occupancy
// (32.7->20.2%) and regressed 49.5->56.1us: attn's independent blocks were
// already hiding staging latency via cross-block TLP (depth>TLP holds only
// for lockstep GEMM blocks). Kept from r20: T12 v_cvt_pk_bf16_f32 packing
// (2 ops vs 4 bit-adds + 2 perms; RTNE <=1ulp bf16).
__global__ __launch_bounds__(512) void attn(
    const unsigned short* __restrict__ qb,  // [B,H,S,HD] pre-scaled (incl. log2e)
    const unsigned short* __restrict__ kb,  // [B,H,S,HD]
    const unsigned short* __restrict__ vb,  // [B,H,HD,S] (transposed)
    unsigned short* __restrict__ ob) {      // [B,S,D]
    int bh = blockIdx.y;
    int q0 = blockIdx.x * 128;
    int tid = threadIdx.x, lane = tid & 63, wave = tid >> 6;
    int grp = wave >> 2;      // k-half
    int w4  = wave & 3;       // wave-in-group: owns q rows w4*32..+31
    int lm = lane & 15, lq = lane >> 4;

    // [pair 2][KA|KB|VA|VB, 4096 shorts each] = 32768 shorts = 64 KB
    __shared__ unsigned short smem[32768];
    float* smf = (float*)smem;

    const unsigned short* qg = qb + (size_t)bh * SS * HDIM;
    const unsigned short* kg = kb + (size_t)bh * SS * HDIM;
    const unsigned short* vg = vb + (size_t)bh * HDIM * SS;

    // Q fragments (both groups load the same q rows for their k-half)
    U4S8 qf[2][2];
    #pragma unroll
    for (int qt = 0; qt < 2; qt++)
        #pragma unroll
        for (int ks = 0; ks < 2; ks++)
            qf[qt][ks].u = *(const uint4*)(
                qg + (size_t)(q0 + w4 * 32 + qt * 16 + lm) * HDIM + ks * 32 + lq * 8);

    f32x4 oacc[4][2] = {};        // O^T[hd-tile][q-subtile] (this group's k-half)
    f32x2 lsum2[2] = {};

    // ---- loop-invariant swizzled LDS read indices within a 64x64 tile (shorts)
    int lm7 = lm & 7;
    int kidx = lm * 64 + 8 * (lq ^ lm7);          // kf b128 (slot rows)
    int vidx[2];                                  // vf b128: kpos kb*32+lq*8 (true k)
    #pragma unroll
    for (int kblk = 0; kblk < 2; kblk++)
        vidx[kblk] = lm * 64 + 8 * (((kblk << 2) | lq) ^ lm7);

    // ---- staging: 512 threads x 4 async-16B = one 128-wide K-tile (K + V)
    // K source row is KAPPA-permuted: LDS slot s holds k-row kappa(s), where
    // kappa(s) = 32*(s>>5) + 8*((s>>2)&3) + 4*((s>>4)&1) + (s&3)  (s in 0..63)
    int sr  = tid >> 3;                // LDS slot row 0..63
    int s5  = sr & 31;
    int kap = (sr & 32) + (((s5 >> 2) & 3) << 3) + (((s5 >> 4) & 1) << 2) + (s5 & 3);
    int lch = (tid & 7) ^ (sr & 7);    // chunk swizzle keyed by SLOT row
    int sdst = tid * 8;                // shorts within each 4096-short region
    const unsigned short* kpA = kg + (size_t)kap * HDIM + lch * 8;   // slots 0-63
    const unsigned short* kpB = kpA + 64 * HDIM;                     // slots 64-127
    const unsigned short* vpA = vg + (size_t)sr * SS + lch * 8;      // kpos 0-63
    const unsigned short* vpB = vpA + 64;                            // kpos 64-127

    #define STAGE(pbase)                                                       \
        do {                                                                   \
            async_cp16(kpA, smem + (pbase) + sdst);                            \
            async_cp16(kpB, smem + (pbase) + 4096 + sdst);                     \
            async_cp16(vpA, smem + (pbase) + 8192 + sdst);                     \
            async_cp16(vpB, smem + (pbase) + 12288 + sdst);                    \
            kpA += 128 * HDIM; kpB += 128 * HDIM; vpA += 128; vpB += 128;      \
        } while (0)

    STAGE(0);

    for (int kt = 0; kt < SS / 128; kt += 2) {
        #pragma unroll
        for (int hf = 0; hf < 2; hf++) {
            int cbase = hf ? 16384 : 0;      // compute pair
            int obase = hf ? 0 : 16384;      // stage target pair
            __syncthreads();  // drains vmcnt: compute pair's loads landed
            STAGE(obase);  // last iter over-reads one tile into adjacent ws buf

            int kbase = cbase + grp * 4096;
            int vbase = cbase + 8192 + grp * 4096;

            // ---- S^T then P^T = 2^(S^T): tile-pair halves fill the K=32
            //      B-operand directly (kappa staging makes r-index == j)
            U4S8 pb8[2][2];   // [kblk][qt]: full 16x16x32 B-operand fragments
            #pragma unroll
            for (int mi = 0; mi < 4; mi++) {
                U4S8 kf0, kf1;
                kf0.u = *(const uint4*)(smem + kbase + mi * 1024 + kidx);
                kf1.u = *(const uint4*)(smem + kbase + mi * 1024 + (kidx ^ 32));
                #pragma unroll
                for (int qt = 0; qt < 2; qt++) {
                    f32x4 sa = {};
                    sa = __builtin_amdgcn_mfma_f32_16x16x32_bf16(kf0.s, qf[qt][0].s, sa, 0, 0, 0);
                    sa = __builtin_amdgcn_mfma_f32_16x16x32_bf16(kf1.s, qf[qt][1].s, sa, 0, 0, 0);
                    float p0 = EXP2(sa[0]);
                    float p1 = EXP2(sa[1]);
                    float p2 = EXP2(sa[2]);
                    float p3 = EXP2(sa[3]);
                    f32x2 a01; a01[0] = p0; a01[1] = p1;
                    f32x2 a23; a23[0] = p2; a23[1] = p3;
                    lsum2[qt] += a01;
                    lsum2[qt] += a23;
                    unsigned int lo, hi;   // T12: pack 2 f32 -> 2 bf16, one op each
                    asm("v_cvt_pk_bf16_f32 %0, %1, %2" : "=v"(lo) : "v"(p0), "v"(p1));
                    asm("v_cvt_pk_bf16_f32 %0, %1, %2" : "=v"(hi) : "v"(p2), "v"(p3));
                    if ((mi & 1) == 0) { pb8[mi >> 1][qt].u.x = lo; pb8[mi >> 1][qt].u.y = hi; }
                    else               { pb8[mi >> 1][qt].u.z = lo; pb8[mi >> 1][qt].u.w = hi; }
                }
            }

            // ---- O^T += V^T·P^T at K=32
            #pragma unroll
            for (int mi2 = 0; mi2 < 4; mi2++) {
                #pragma unroll
                for (int kblk = 0; kblk < 2; kblk++) {
                    U4S8 vf;
                    vf.u = *(const uint4*)(smem + vbase + mi2 * 1024 + vidx[kblk]);
                    oacc[mi2][0] = __builtin_amdgcn_mfma_f32_16x16x32_bf16(
                        vf.s, pb8[kblk][0].s, oacc[mi2][0], 0, 0, 0);
                    oacc[mi2][1] = __builtin_amdgcn_mfma_f32_16x16x32_bf16(
                        vf.s, pb8[kblk][1].s, oacc[mi2][1], 0, 0, 0);
                }
            }
        }
    }
    #undef STAGE

    // ---- per-group row sums (lanes lm,+16,+32,+48 hold disjoint k partials)
    float gsum[2];
    #pragma unroll
    for (int qt = 0; qt < 2; qt++) {
        float s = lsum2[qt][0] + lsum2[qt][1];
        s += __shfl_xor(s, 16);
        s += __shfl_xor(s, 32);
        gsum[qt] = s;
    }

    __syncthreads();  // all compute done; drains stray over-read loads

    // ---- group 1 publishes raw O^T + sums (SoA: word j at j*64+lane, no conflicts)
    if (grp == 1) {
        float* pub = smf + w4 * 2048;
        #pragma unroll
        for (int mi2 = 0; mi2 < 4; mi2++)
            #pragma unroll
            for (int qt = 0; qt < 2; qt++)
                #pragma unroll
                for (int r = 0; r < 4; r++)
                    pub[(mi2 * 8 + qt * 4 + r) * 64 + lane] = oacc[mi2][qt][r];
        if (lq == 0) {
            smf[8192 + w4 * 32 + lm]      = gsum[0];
            smf[8192 + w4 * 32 + 16 + lm] = gsum[1];
        }
    }
    __syncthreads();

    // ---- group 0 combines, normalizes, writes output
    if (grp == 0) {
        float* pub = smf + w4 * 2048;
        #pragma unroll
        for (int mi2 = 0; mi2 < 4; mi2++)
            #pragma unroll
            for (int qt = 0; qt < 2; qt++)
                #pragma unroll
                for (int r = 0; r < 4; r++)
                    oacc[mi2][qt][r] += pub[(mi2 * 8 + qt * 4 + r) * 64 + lane];
        float inv[2];
        inv[0] = 1.f / (gsum[0] + smf[8192 + w4 * 32 + lm]);
        inv[1] = 1.f / (gsum[1] + smf[8192 + w4 * 32 + 16 + lm]);

        // transpose O^T back via smem (region disjoint from publish), coalesced store
        unsigned short* Ow = smem + 17024 + w4 * 2304;  // 32 x 72
        #pragma unroll
        for (int mi2 = 0; mi2 < 4; mi2++)
            #pragma unroll
            for (int qt = 0; qt < 2; qt++) {
                U2S4 t;
                #pragma unroll
                for (int r = 0; r < 4; r++)
                    t.h[r] = f2bf(oacc[mi2][qt][r] * inv[qt]);
                *(uint2*)&Ow[(qt * 16 + lm) * 72 + mi2 * 16 + lq * 4] = t.u;
            }
        __builtin_amdgcn_wave_barrier();  // Ow wave-local
        int b = bh >> 4, h = bh & 15;
        #pragma unroll
        for (int it = 0; it < 4; it++) {
            int q  = it * 8 + (lane >> 3);
            int off = (lane & 7) * 8;
            uint4 val = *(const uint4*)&Ow[q * 72 + off];
            int srw = q0 + w4 * 32 + q;
            *(uint4*)(ob + (size_t)(b * SS + srw) * DD + h * 64 + off) = val;
        }
    }
}

// ---------------------------------------------------------------- Output GEMM
// out[m,e] = sum_d o[m,d] * w_out[e,d] + b_out[e].  M=4096, N=1024, K=1024.
// r21: r19 ring ported. 128x64 tile, BK=32, 4-deep ring (4 x 12KB = 48KB,
// ~3 blocks/CU), 3 staging ops/K-tile, ONE vmcnt(6) + ONE barrier per
// K-tile -> 2-3 tiles of staging slack (was 2-phase drain -- r18 disease).
// Tail A-prefetch clamped to kk=0: A (o_buf) is the LAST ws buffer, an
// unclamped t>=29 prefetch would read past the workspace; clamped ops land
// in a ring slot that is never consumed. B (wout_bf) tail over-reads into
// q_buf (in-bounds). LDS[u][c] = global[row][c ^ (u&3)], same swizzle as
// gemm_qkv; buf layout (shorts): A0[0,2048) A1[2048,4096) B[4096,6144).
__global__ __launch_bounds__(256) void gemm_out(
    const unsigned short* __restrict__ A,   // o_bf   [4096][1024]
    const unsigned short* __restrict__ Bw,  // wout_bf[1024][1024]
    const float* __restrict__ bias, float* __restrict__ out) {
    const int K = 1024;
    __shared__ unsigned short smem[24576];  // 48 KB: 4 bufs x 6144 shorts
    int tid = threadIdx.x;
    int lane = tid & 63, wave = tid >> 6;
    int wm = (wave & 1) * 64, wn = (wave >> 1) * 32;
    int m0 = blockIdx.y * 128, n0 = blockIdx.x * 64;
    int lm = lane & 15, lq = lane >> 4;

    f32x4 acc[4][2] = {};

    // ---- staging addressing (pre-swizzled global source, linear LDS dest)
    int u = tid >> 2;                        // row-within-op 0..63
    int c2 = (tid & 3) ^ (u & 3);            // swizzled source chunk
    int sdst = tid * 8;                      // LDS dest within op region
    const unsigned short* gA0 = A  + (size_t)(m0 + u) * K + c2 * 8;
    const unsigned short* gA1 = gA0 + (size_t)64 * K;
    const unsigned short* gB0 = Bw + (size_t)(n0 + u) * K + c2 * 8;

#define OSTG(j, kk) do {                                                   \
        async_cp16(gA0 + (kk), smem + (j) * 6144 + sdst);                  \
        async_cp16(gA1 + (kk), smem + (j) * 6144 + 2048 + sdst);           \
        async_cp16(gB0 + (kk), smem + (j) * 6144 + 4096 + sdst);           \
    } while (0)

    // ---- fragment read addressing (swizzled chunk)
    int axk = (lq ^ (lm & 3)) * 8;
    int aBase = (wm + lm) * 32 + axk;
    int bBase = 4096 + (wn + lm) * 32 + axk;

    // prologue: stage tiles 0,1,2 (9 ops); vmcnt(6) retires tile 0's 3 ops.
    OSTG(0, 0); OSTG(1, 32); OSTG(2, 64);
    asm volatile("s_waitcnt vmcnt(6)" ::: "memory");
    __builtin_amdgcn_s_barrier();

    // 32 K-tiles of BK=32; stage tile t+3 (kk clamped for t>=29: A is the
    // last ws buffer). vmcnt(6) retires tile t+1's ops; t+2/t+3 in flight.
    #pragma unroll 1
    for (int t = 0; t < 32; ++t) {
        int cb = (t & 3) * 6144;
        int kks = (t + 3 < 32) ? (t + 3) * 32 : 0;
        U4S8 af[4], bfx[2];
        #pragma unroll
        for (int m = 0; m < 4; m++)
            af[m].u = *(const uint4*)(smem + cb + aBase + m * 512);
        #pragma unroll
        for (int n = 0; n < 2; n++)
            bfx[n].u = *(const uint4*)(smem + cb + bBase + n * 512);
        OSTG((t + 3) & 3, kks);
        #pragma unroll
        for (int m = 0; m < 4; m++)
            #pragma unroll
            for (int n = 0; n < 2; n++)
                acc[m][n] = __builtin_amdgcn_mfma_f32_16x16x32_bf16(
                    af[m].s, bfx[n].s, acc[m][n], 0, 0, 0);
        asm volatile("s_waitcnt vmcnt(6)" ::: "memory");
        __builtin_amdgcn_s_barrier();
    }
#undef OSTG

    asm volatile("s_waitcnt vmcnt(0)" ::: "memory");  // drain clamped tail loads

    #pragma unroll
    for (int mi = 0; mi < 4; mi++) {
        int gr = m0 + wm + mi * 16 + lq * 4;
        #pragma unroll
        for (int ni = 0; ni < 2; ni++) {
            int gc = n0 + wn + ni * 16 + lm;
            float bv = bias[gc];
            #pragma unroll
            for (int r = 0; r < 4; r++)
                out[(size_t)(gr + r) * DD + gc] = acc[mi][ni][r] + bv;
        }
    }
}

// ---------------------------------------------------------------- launch
extern "C" void kernel_launch(void* const* d_in, const int* in_sizes, int n_in,
                              void* d_out, int out_size, void* d_ws, size_t ws_size,
                              hipStream_t stream) {
    const float* x     = (const float*)d_in[0];
    const float* w_qkv = (const float*)d_in[1];
    const float* w_out = (const float*)d_in[2];
    const float* b_out = (const float*)d_in[3];
    float* out = (float*)d_out;

    unsigned short* ws = (unsigned short*)d_ws;
    const size_t NX = (size_t)BB * SS * DD;        // 4,194,304
    unsigned short* x_bf    = ws;
    unsigned short* wqkv_bf = x_bf + NX;
    unsigned short* wout_bf = wqkv_bf + 3145728;
    unsigned short* q_buf   = wout_bf + 1048576;
    unsigned short* k_buf   = q_buf + NX;
    unsigned short* v_buf   = k_buf + NX;
    unsigned short* o_buf   = v_buf + NX;

    cvt_all<<<4096, 256, 0, stream>>>(x, w_qkv, w_out, x_bf, wqkv_bf, wout_bf);
    gemm_qkv<<<dim3(12, 16), 512, 0, stream>>>(x_bf, wqkv_bf, q_buf, k_buf, v_buf);
    attn<<<dim3(16, 32), 512, 0, stream>>>(q_buf, k_buf, v_buf, o_buf);
    gemm_out<<<dim3(16, 32), 256, 0, stream>>>(o_buf, wout_bf, b_out, out);
}

// Round 15
// 171.111 us; speedup vs baseline: 1.0845x; 1.0056x over previous
//
#include <hip/hip_runtime.h>
#include <cstdint>
#include <cstddef>

// Problem constants
#define BB 2
#define SS 2048
#define DD 1024
#define HH 16
#define HDIM 64
// Attention scale 1/sqrt(64)=0.125 and the exp->exp2 fold log2(e) are
// pre-multiplied into q at the gemm_qkv epilogue: 0.125*1.4426950 = 0.18033688.

typedef short bf16x8 __attribute__((ext_vector_type(8)));
typedef short bf16x4 __attribute__((ext_vector_type(4)));
typedef float f32x4 __attribute__((ext_vector_type(4)));
typedef float f32x2 __attribute__((ext_vector_type(2)));

union U4S8 { uint4 u; bf16x8 s; };
union U2S4 { uint2 u; bf16x4 s; unsigned short h[4]; };

#if defined(__HIP_DEVICE_COMPILE__)
# if __has_builtin(__builtin_amdgcn_exp2f)
#  define EXP2(x) __builtin_amdgcn_exp2f(x)   // bare v_exp_f32, no libm envelope
# else
#  define EXP2(x) exp2f(x)
# endif
#else
# define EXP2(x) exp2f(x)
#endif

__device__ __forceinline__ unsigned short f2bf(float f) {
    union { float f; unsigned int u; } c; c.f = f;
    unsigned int u = c.u;
    unsigned int r = (u + 0x7FFFu + ((u >> 16) & 1u)) >> 16;  // RTNE
    return (unsigned short)r;
}

// async global->LDS, 16B per lane. LDS dest must be wave-uniform base + lane*16.
__device__ __forceinline__ void async_cp16(const void* g, void* l) {
    __builtin_amdgcn_global_load_lds(
        (const __attribute__((address_space(1))) void*)g,
        (__attribute__((address_space(3))) void*)l, 16, 0, 0);
}

// ---------------------------------------------------------------- fp32 -> bf16
// One kernel for all three inputs (x:524288, w_qkv:393216, w_out:131072 uint4s).
__global__ __launch_bounds__(256) void cvt_all(
    const float* __restrict__ x, const float* __restrict__ wq,
    const float* __restrict__ wo,
    unsigned short* __restrict__ xb, unsigned short* __restrict__ wqb,
    unsigned short* __restrict__ wob) {
    int i = blockIdx.x * 256 + threadIdx.x;
    const float* in; unsigned short* out; int j;
    if (i < 524288)       { in = x;  out = xb;  j = i; }
    else if (i < 917504)  { in = wq; out = wqb; j = i - 524288; }
    else                  { in = wo; out = wob; j = i - 917504; }
    float4 a = ((const float4*)in)[2 * j];
    float4 b = ((const float4*)in)[2 * j + 1];
    union { uint4 u; unsigned short h[8]; } o;
    o.h[0] = f2bf(a.x); o.h[1] = f2bf(a.y); o.h[2] = f2bf(a.z); o.h[3] = f2bf(a.w);
    o.h[4] = f2bf(b.x); o.h[5] = f2bf(b.y); o.h[6] = f2bf(b.z); o.h[7] = f2bf(b.w);
    ((uint4*)out)[j] = o.u;
}

// ---------------------------------------------------------------- QKV GEMM
// C[m,e] = sum_d x[m,d] * w_qkv[e,d]  (NT). M=4096, N=3072, K=1024.
// r19 (MEASURED WIN): BK=32, 4-deep LDS ring (4 x 32KB = 128KB), stage tile
// t+3 during tile t, ONE vmcnt(8) + ONE barrier per K-tile. Unchanged.
__global__ __launch_bounds__(512, 2) void gemm_qkv(
    const unsigned short* __restrict__ A,   // x_bf   [4096][1024]
    const unsigned short* __restrict__ Bw,  // wqkv_bf[3072][1024]
    unsigned short* __restrict__ qb, unsigned short* __restrict__ kb,
    unsigned short* __restrict__ vb) {
    const int K = 1024;
    __shared__ unsigned short smem[65536];  // 128 KB: 4 bufs x [A 8192 | B 8192]
    int tid = threadIdx.x;
    int lane = tid & 63, wave = tid >> 6;
    int wmp = wave & 1, wnp = wave >> 1;
    int lm = lane & 15, lq = lane >> 4;

    // XCD-chunked bijective swizzle: 192 blocks = 8 XCDs x 24
    int id = blockIdx.y * 12 + blockIdx.x;
    int swz = (id & 7) * 24 + (id >> 3);
    int m0 = (swz / 12) * 256, n0 = (swz % 12) * 256;

    f32x4 acc[8][4] = {};

    // ---- staging addressing (pre-swizzled global source, linear LDS dest)
    int u2 = tid >> 2;                        // row-within-op 0..127
    int c2 = (tid & 3) ^ (u2 & 3);            // swizzled source chunk
    int sdst = tid * 8;                       // LDS dest (shorts)
    const unsigned short* gA0 = A  + (size_t)(m0 + u2) * K + c2 * 8;
    const unsigned short* gB0 = Bw + (size_t)(n0 + u2) * K + c2 * 8;
    const unsigned short* gA1 = gA0 + (size_t)128 * K;
    const unsigned short* gB1 = gB0 + (size_t)128 * K;

    // stage all 4 ops of one K-tile into buf j at column kk (shorts)
#define STAGE4(j, kk) do {                                                  \
        async_cp16(gA0 + (kk), smem + (j) * 16384 + 0     + sdst);          \
        async_cp16(gA1 + (kk), smem + (j) * 16384 + 4096  + sdst);          \
        async_cp16(gB0 + (kk), smem + (j) * 16384 + 8192  + sdst);          \
        async_cp16(gB1 + (kk), smem + (j) * 16384 + 12288 + sdst);          \
    } while (0)

    // ---- fragment read addressing (swizzled chunk, balanced banks)
    int axk = (lq ^ (lm & 3)) * 8;
    int aBase = (wmp * 128 + lm) * 32 + axk;
    int bBase = 8192 + (wnp * 64 + lm) * 32 + axk;
    U4S8 af[8], bfr[4];

    // One K-tile: 12 ds_read_b128 + 4 staging ops (tile t+3) + 32 MFMA +
    // vmcnt(8) (retires tile t+1's 4 ops; t+2/t+3 stay in flight) + barrier.
#define KT(j, kk3) do {                                                     \
        _Pragma("unroll")                                                   \
        for (int m = 0; m < 8; m++)                                         \
            af[m].u = *(const uint4*)(smem + (j) * 16384 + aBase + m * 512);\
        _Pragma("unroll")                                                   \
        for (int n = 0; n < 4; n++)                                         \
            bfr[n].u = *(const uint4*)(smem + (j) * 16384 + bBase + n * 512);\
        STAGE4((((j) + 3) & 3), kk3);                                       \
        _Pragma("unroll")                                                   \
        for (int m = 0; m < 8; m++)                                         \
            _Pragma("unroll")                                               \
            for (int n = 0; n < 4; n++)                                     \
                acc[m][n] = __builtin_amdgcn_mfma_f32_16x16x32_bf16(        \
                    af[m].s, bfr[n].s, acc[m][n], 0, 0, 0);                 \
        asm volatile("s_waitcnt vmcnt(8)" ::: "memory");                    \
        __builtin_amdgcn_s_barrier();                                       \
    } while (0)

    // prologue: stage tiles 0,1,2 (12 ops, tile-FIFO order); vmcnt(8)
    // retires tile 0's 4 ops before the first read.
    STAGE4(0, 0); STAGE4(1, 32); STAGE4(2, 64);
    asm volatile("s_waitcnt vmcnt(8)" ::: "memory");
    __builtin_amdgcn_s_barrier();

    // 32 K-tiles of BK=32; prefetch kk = (t+3)*32. Tail prefetches (t>=29)
    // over-read into adjacent ws buffers (never consumed, in-bounds of ws).
    #pragma unroll 1
    for (int t4 = 0; t4 < 8; ++t4) {
        int kb128 = t4 * 128;
        KT(0, kb128 + 96);
        KT(1, kb128 + 128);
        KT(2, kb128 + 160);
        KT(3, kb128 + 192);
    }
#undef KT
#undef STAGE4

    asm volatile("s_waitcnt vmcnt(0)" ::: "memory");  // drain stray over-read loads
    __builtin_amdgcn_s_barrier();                     // staging LDS done before reuse

    // Epilogue. C/D layout: col=lane&15, row=(lane>>4)*4+reg.
    unsigned short* Lw = smem + wave * 8192;  // uses 64 x 72
    int wm = wmp * 128, wn = wnp * 64;
    int b = m0 >> 11;
    int s_base = (m0 + wm) & 2047;
    int h = ((n0 + wn) >> 6) & 15;
    if (n0 < 1024) {
        // ---- v: transpose (store [B,H,HD,S]): Lw[hd][s], b64 packed writes
        unsigned short* vdst = vb + ((size_t)(b * HH + h) * HDIM) * SS;
        #pragma unroll
        for (int c = 0; c < 2; c++) {
            #pragma unroll
            for (int m4 = 0; m4 < 4; m4++)
                #pragma unroll
                for (int ni = 0; ni < 4; ni++) {
                    U2S4 t;
                    #pragma unroll
                    for (int r = 0; r < 4; r++)
                        t.h[r] = f2bf(acc[c * 4 + m4][ni][r]);
                    *(uint2*)&Lw[(ni * 16 + lm) * 72 + m4 * 16 + lq * 4] = t.u;
                }
            __builtin_amdgcn_wave_barrier();
            #pragma unroll
            for (int it = 0; it < 8; it++) {
                int hd = it * 8 + (lane >> 3);
                int so = (lane & 7) * 8;
                uint4 val = *(const uint4*)&Lw[hd * 72 + so];
                *(uint4*)(vdst + (size_t)hd * SS + s_base + c * 64 + so) = val;
            }
            __builtin_amdgcn_wave_barrier();
        }
    } else {
        // ---- q/k: gather (store [B,H,S,HD]): Lw[s][hd], no transpose
        bool isq = n0 < 2048;
        unsigned short* dst = isq ? qb : kb;
        float scale = isq ? 0.18033688f : 1.0f;  // q: fold softmax scale * log2(e)
        unsigned short* qdst = dst + ((size_t)(b * HH + h) * SS) * HDIM;
        #pragma unroll
        for (int c = 0; c < 2; c++) {
            #pragma unroll
            for (int m4 = 0; m4 < 4; m4++)
                #pragma unroll
                for (int ni = 0; ni < 4; ni++)
                    #pragma unroll
                    for (int r = 0; r < 4; r++)
                        Lw[(m4 * 16 + lq * 4 + r) * 72 + ni * 16 + lm] =
                            f2bf(acc[c * 4 + m4][ni][r] * scale);
            __builtin_amdgcn_wave_barrier();
            #pragma unroll
            for (int it = 0; it < 8; it++) {
                int srw = it * 8 + (lane >> 3);
                int so = (lane & 7) * 8;
                uint4 val = *(const uint4*)&Lw[srw * 72 + so];
                *(uint4*)(qdst + (size_t)(s_base + c * 64 + srw) * HDIM + so) = val;
            }
            __builtin_amdgcn_wave_barrier();
        }
    }
}

// ---------------------------------------------------------------- Flash attention
// r22: r21 structure (measured best: 45.3us) + two orthogonal adds:
// (1) XCD-gather swizzle: r21 FETCH=73.8MB vs ~24MB ideal -- linear id
//     (bh*16+q0) round-robins XCDs, so the 16 q0-blocks sharing one bh's
//     K/V (512KB) land on DIFFERENT XCDs' L2s -> ~3x refetch. Remap
//     bh=(id&7)*4+((id>>3)&3), q0=(id>>5)*128 (bijective 8*4*16=512):
//     all 16 blocks of a bh -> same XCD; 4 bh/XCD x 512KB = 2MB < 4MB L2.
// (2) T5 setprio(1) around QK and PV MFMA pairs (+4-7% measured on attn
//     with this independent-block structure, learn_hip m191).
__global__ __launch_bounds__(512) void attn(
    const unsigned short* __restrict__ qb,  // [B,H,S,HD] pre-scaled (incl. log2e)
    const unsigned short* __restrict__ kb,  // [B,H,S,HD]
    const unsigned short* __restrict__ vb,  // [B,H,HD,S] (transposed)
    unsigned short* __restrict__ ob) {      // [B,S,D]
    int id = blockIdx.y * 16 + blockIdx.x;
    int bh = (id & 7) * 4 + ((id >> 3) & 3);
    int q0 = (id >> 5) * 128;
    int tid = threadIdx.x, lane = tid & 63, wave = tid >> 6;
    int grp = wave >> 2;      // k-half
    int w4  = wave & 3;       // wave-in-group: owns q rows w4*32..+31
    int lm = lane & 15, lq = lane >> 4;

    // [pair 2][KA|KB|VA|VB, 4096 shorts each] = 32768 shorts = 64 KB
    __shared__ unsigned short smem[32768];
    float* smf = (float*)smem;

    const unsigned short* qg = qb + (size_t)bh * SS * HDIM;
    const unsigned short* kg = kb + (size_t)bh * SS * HDIM;
    const unsigned short* vg = vb + (size_t)bh * HDIM * SS;

    // Q fragments (both groups load the same q rows for their k-half)
    U4S8 qf[2][2];
    #pragma unroll
    for (int qt = 0; qt < 2; qt++)
        #pragma unroll
        for (int ks = 0; ks < 2; ks++)
            qf[qt][ks].u = *(const uint4*)(
                qg + (size_t)(q0 + w4 * 32 + qt * 16 + lm) * HDIM + ks * 32 + lq * 8);

    f32x4 oacc[4][2] = {};        // O^T[hd-tile][q-subtile] (this group's k-half)
    f32x2 lsum2[2] = {};

    // ---- loop-invariant swizzled LDS read indices within a 64x64 tile (shorts)
    int lm7 = lm & 7;
    int kidx = lm * 64 + 8 * (lq ^ lm7);          // kf b128 (slot rows)
    int vidx[2];                                  // vf b128: kpos kb*32+lq*8 (true k)
    #pragma unroll
    for (int kblk = 0; kblk < 2; kblk++)
        vidx[kblk] = lm * 64 + 8 * (((kblk << 2) | lq) ^ lm7);

    // ---- staging: 512 threads x 4 async-16B = one 128-wide K-tile (K + V)
    // K source row is KAPPA-permuted: LDS slot s holds k-row kappa(s), where
    // kappa(s) = 32*(s>>5) + 8*((s>>2)&3) + 4*((s>>4)&1) + (s&3)  (s in 0..63)
    int sr  = tid >> 3;                // LDS slot row 0..63
    int s5  = sr & 31;
    int kap = (sr & 32) + (((s5 >> 2) & 3) << 3) + (((s5 >> 4) & 1) << 2) + (s5 & 3);
    int lch = (tid & 7) ^ (sr & 7);    // chunk swizzle keyed by SLOT row
    int sdst = tid * 8;                // shorts within each 4096-short region
    const unsigned short* kpA = kg + (size_t)kap * HDIM + lch * 8;   // slots 0-63
    const unsigned short* kpB = kpA + 64 * HDIM;                     // slots 64-127
    const unsigned short* vpA = vg + (size_t)sr * SS + lch * 8;      // kpos 0-63
    const unsigned short* vpB = vpA + 64;                            // kpos 64-127

    #define STAGE(pbase)                                                       \
        do {                                                                   \
            async_cp16(kpA, smem + (pbase) + sdst);                            \
            async_cp16(kpB, smem + (pbase) + 4096 + sdst);                     \
            async_cp16(vpA, smem + (pbase) + 8192 + sdst);                     \
            async_cp16(vpB, smem + (pbase) + 12288 + sdst);                    \
            kpA += 128 * HDIM; kpB += 128 * HDIM; vpA += 128; vpB += 128;      \
        } while (0)

    STAGE(0);

    for (int kt = 0; kt < SS / 128; kt += 2) {
        #pragma unroll
        for (int hf = 0; hf < 2; hf++) {
            int cbase = hf ? 16384 : 0;      // compute pair
            int obase = hf ? 0 : 16384;      // stage target pair
            __syncthreads();  // drains vmcnt: compute pair's loads landed
            STAGE(obase);  // last iter over-reads one tile into adjacent ws buf

            int kbase = cbase + grp * 4096;
            int vbase = cbase + 8192 + grp * 4096;

            // ---- S^T then P^T = 2^(S^T): tile-pair halves fill the K=32
            //      B-operand directly (kappa staging makes r-index == j)
            U4S8 pb8[2][2];   // [kblk][qt]: full 16x16x32 B-operand fragments
            #pragma unroll
            for (int mi = 0; mi < 4; mi++) {
                U4S8 kf0, kf1;
                kf0.u = *(const uint4*)(smem + kbase + mi * 1024 + kidx);
                kf1.u = *(const uint4*)(smem + kbase + mi * 1024 + (kidx ^ 32));
                #pragma unroll
                for (int qt = 0; qt < 2; qt++) {
                    f32x4 sa = {};
                    __builtin_amdgcn_s_setprio(1);
                    sa = __builtin_amdgcn_mfma_f32_16x16x32_bf16(kf0.s, qf[qt][0].s, sa, 0, 0, 0);
                    sa = __builtin_amdgcn_mfma_f32_16x16x32_bf16(kf1.s, qf[qt][1].s, sa, 0, 0, 0);
                    __builtin_amdgcn_s_setprio(0);
                    float p0 = EXP2(sa[0]);
                    float p1 = EXP2(sa[1]);
                    float p2 = EXP2(sa[2]);
                    float p3 = EXP2(sa[3]);
                    f32x2 a01; a01[0] = p0; a01[1] = p1;
                    f32x2 a23; a23[0] = p2; a23[1] = p3;
                    lsum2[qt] += a01;
                    lsum2[qt] += a23;
                    unsigned int lo, hi;   // T12: pack 2 f32 -> 2 bf16, one op each
                    asm("v_cvt_pk_bf16_f32 %0, %1, %2" : "=v"(lo) : "v"(p0), "v"(p1));
                    asm("v_cvt_pk_bf16_f32 %0, %1, %2" : "=v"(hi) : "v"(p2), "v"(p3));
                    if ((mi & 1) == 0) { pb8[mi >> 1][qt].u.x = lo; pb8[mi >> 1][qt].u.y = hi; }
                    else               { pb8[mi >> 1][qt].u.z = lo; pb8[mi >> 1][qt].u.w = hi; }
                }
            }

            // ---- O^T += V^T·P^T at K=32
            #pragma unroll
            for (int mi2 = 0; mi2 < 4; mi2++) {
                #pragma unroll
                for (int kblk = 0; kblk < 2; kblk++) {
                    U4S8 vf;
                    vf.u = *(const uint4*)(smem + vbase + mi2 * 1024 + vidx[kblk]);
                    __builtin_amdgcn_s_setprio(1);
                    oacc[mi2][0] = __builtin_amdgcn_mfma_f32_16x16x32_bf16(
                        vf.s, pb8[kblk][0].s, oacc[mi2][0], 0, 0, 0);
                    oacc[mi2][1] = __builtin_amdgcn_mfma_f32_16x16x32_bf16(
                        vf.s, pb8[kblk][1].s, oacc[mi2][1], 0, 0, 0);
                    __builtin_amdgcn_s_setprio(0);
                }
            }
        }
    }
    #undef STAGE

    // ---- per-group row sums (lanes lm,+16,+32,+48 hold disjoint k partials)
    float gsum[2];
    #pragma unroll
    for (int qt = 0; qt < 2; qt++) {
        float s = lsum2[qt][0] + lsum2[qt][1];
        s += __shfl_xor(s, 16);
        s += __shfl_xor(s, 32);
        gsum[qt] = s;
    }

    __syncthreads();  // all compute done; drains stray over-read loads

    // ---- group 1 publishes raw O^T + sums (SoA: word j at j*64+lane, no conflicts)
    if (grp == 1) {
        float* pub = smf + w4 * 2048;
        #pragma unroll
        for (int mi2 = 0; mi2 < 4; mi2++)
            #pragma unroll
            for (int qt = 0; qt < 2; qt++)
                #pragma unroll
                for (int r = 0; r < 4; r++)
                    pub[(mi2 * 8 + qt * 4 + r) * 64 + lane] = oacc[mi2][qt][r];
        if (lq == 0) {
            smf[8192 + w4 * 32 + lm]      = gsum[0];
            smf[8192 + w4 * 32 + 16 + lm] = gsum[1];
        }
    }
    __syncthreads();

    // ---- group 0 combines, normalizes, writes output
    if (grp == 0) {
        float* pub = smf + w4 * 2048;
        #pragma unroll
        for (int mi2 = 0; mi2 < 4; mi2++)
            #pragma unroll
            for (int qt = 0; qt < 2; qt++)
                #pragma unroll
                for (int r = 0; r < 4; r++)
                    oacc[mi2][qt][r] += pub[(mi2 * 8 + qt * 4 + r) * 64 + lane];
        float inv[2];
        inv[0] = 1.f / (gsum[0] + smf[8192 + w4 * 32 + lm]);
        inv[1] = 1.f / (gsum[1] + smf[8192 + w4 * 32 + 16 + lm]);

        // transpose O^T back via smem (region disjoint from publish), coalesced store
        unsigned short* Ow = smem + 17024 + w4 * 2304;  // 32 x 72
        #pragma unroll
        for (int mi2 = 0; mi2 < 4; mi2++)
            #pragma unroll
            for (int qt = 0; qt < 2; qt++) {
                U2S4 t;
                #pragma unroll
                for (int r = 0; r < 4; r++)
                    t.h[r] = f2bf(oacc[mi2][qt][r] * inv[qt]);
                *(uint2*)&Ow[(qt * 16 + lm) * 72 + mi2 * 16 + lq * 4] = t.u;
            }
        __builtin_amdgcn_wave_barrier();  // Ow wave-local
        int b = bh >> 4, h = bh & 15;
        #pragma unroll
        for (int it = 0; it < 4; it++) {
            int q  = it * 8 + (lane >> 3);
            int off = (lane & 7) * 8;
            uint4 val = *(const uint4*)&Ow[q * 72 + off];
            int srw = q0 + w4 * 32 + q;
            *(uint4*)(ob + (size_t)(b * SS + srw) * DD + h * 64 + off) = val;
        }
    }
}

// ---------------------------------------------------------------- Output GEMM
// out[m,e] = sum_d o[m,d] * w_out[e,d] + b_out[e].  M=4096, N=1024, K=1024.
// r21 (kept): r19 ring ported. 128x64 tile, BK=32, 4-deep ring (48KB,
// ~3 blocks/CU), ONE vmcnt(6) + ONE barrier per K-tile. Tail A-prefetch
// clamped to kk=0 (A = o_buf is the last ws buffer).
__global__ __launch_bounds__(256) void gemm_out(
    const unsigned short* __restrict__ A,   // o_bf   [4096][1024]
    const unsigned short* __restrict__ Bw,  // wout_bf[1024][1024]
    const float* __restrict__ bias, float* __restrict__ out) {
    const int K = 1024;
    __shared__ unsigned short smem[24576];  // 48 KB: 4 bufs x 6144 shorts
    int tid = threadIdx.x;
    int lane = tid & 63, wave = tid >> 6;
    int wm = (wave & 1) * 64, wn = (wave >> 1) * 32;
    int m0 = blockIdx.y * 128, n0 = blockIdx.x * 64;
    int lm = lane & 15, lq = lane >> 4;

    f32x4 acc[4][2] = {};

    // ---- staging addressing (pre-swizzled global source, linear LDS dest)
    int u = tid >> 2;                        // row-within-op 0..63
    int c2 = (tid & 3) ^ (u & 3);            // swizzled source chunk
    int sdst = tid * 8;                      // LDS dest within op region
    const unsigned short* gA0 = A  + (size_t)(m0 + u) * K + c2 * 8;
    const unsigned short* gA1 = gA0 + (size_t)64 * K;
    const unsigned short* gB0 = Bw + (size_t)(n0 + u) * K + c2 * 8;

#define OSTG(j, kk) do {                                                   \
        async_cp16(gA0 + (kk), smem + (j) * 6144 + sdst);                  \
        async_cp16(gA1 + (kk), smem + (j) * 6144 + 2048 + sdst);           \
        async_cp16(gB0 + (kk), smem + (j) * 6144 + 4096 + sdst);           \
    } while (0)

    // ---- fragment read addressing (swizzled chunk)
    int axk = (lq ^ (lm & 3)) * 8;
    int aBase = (wm + lm) * 32 + axk;
    int bBase = 4096 + (wn + lm) * 32 + axk;

    // prologue: stage tiles 0,1,2 (9 ops); vmcnt(6) retires tile 0's 3 ops.
    OSTG(0, 0); OSTG(1, 32); OSTG(2, 64);
    asm volatile("s_waitcnt vmcnt(6)" ::: "memory");
    __builtin_amdgcn_s_barrier();

    // 32 K-tiles of BK=32; stage tile t+3 (kk clamped for t>=29: A is the
    // last ws buffer). vmcnt(6) retires tile t+1's ops; t+2/t+3 in flight.
    #pragma unroll 1
    for (int t = 0; t < 32; ++t) {
        int cb = (t & 3) * 6144;
        int kks = (t + 3 < 32) ? (t + 3) * 32 : 0;
        U4S8 af[4], bfx[2];
        #pragma unroll
        for (int m = 0; m < 4; m++)
            af[m].u = *(const uint4*)(smem + cb + aBase + m * 512);
        #pragma unroll
        for (int n = 0; n < 2; n++)
            bfx[n].u = *(const uint4*)(smem + cb + bBase + n * 512);
        OSTG((t + 3) & 3, kks);
        #pragma unroll
        for (int m = 0; m < 4; m++)
            #pragma unroll
            for (int n = 0; n < 2; n++)
                acc[m][n] = __builtin_amdgcn_mfma_f32_16x16x32_bf16(
                    af[m].s, bfx[n].s, acc[m][n], 0, 0, 0);
        asm volatile("s_waitcnt vmcnt(6)" ::: "memory");
        __builtin_amdgcn_s_barrier();
    }
#undef OSTG

    asm volatile("s_waitcnt vmcnt(0)" ::: "memory");  // drain clamped tail loads

    #pragma unroll
    for (int mi = 0; mi < 4; mi++) {
        int gr = m0 + wm + mi * 16 + lq * 4;
        #pragma unroll
        for (int ni = 0; ni < 2; ni++) {
            int gc = n0 + wn + ni * 16 + lm;
            float bv = bias[gc];
            #pragma unroll
            for (int r = 0; r < 4; r++)
                out[(size_t)(gr + r) * DD + gc] = acc[mi][ni][r] + bv;
        }
    }
}

// ---------------------------------------------------------------- launch
extern "C" void kernel_launch(void* const* d_in, const int* in_sizes, int n_in,
                              void* d_out, int out_size, void* d_ws, size_t ws_size,
                              hipStream_t stream) {
    const float* x     = (const float*)d_in[0];
    const float* w_qkv = (const float*)d_in[1];
    const float* w_out = (const float*)d_in[2];
    const float* b_out = (const float*)d_in[3];
    float* out = (float*)d_out;

    unsigned short* ws = (unsigned short*)d_ws;
    const size_t NX = (size_t)BB * SS * DD;        // 4,194,304
    unsigned short* x_bf    = ws;
    unsigned short* wqkv_bf = x_bf + NX;
    unsigned short* wout_bf = wqkv_bf + 3145728;
    unsigned short* q_buf   = wout_bf + 1048576;
    unsigned short* k_buf   = q_buf + NX;
    unsigned short* v_buf   = k_buf + NX;
    unsigned short* o_buf   = v_buf + NX;

    cvt_all<<<4096, 256, 0, stream>>>(x, w_qkv, w_out, x_bf, wqkv_bf, wout_bf);
    gemm_qkv<<<dim3(12, 16), 512, 0, stream>>>(x_bf, wqkv_bf, q_buf, k_buf, v_buf);
    attn<<<dim3(16, 32), 512, 0, stream>>>(q_buf, k_buf, v_buf, o_buf);
    gemm_out<<<dim3(16, 32), 256, 0, stream>>>(o_buf, wout_bf, b_out, out);
}